// Round 8
// baseline (209.396 us; speedup 1.0000x reference)
//
#include <hip/hip_runtime.h>
#include <hip/hip_cooperative_groups.h>

namespace cg = cooperative_groups;

// StatefulFormantFilter: B=32, T=48000, F=5
// y[t] = x[t] + 2 r cos(th) y[t-1] - r^2 y[t-2],  r=exp(-pi bw/SR), th=2 pi cf/SR
// x = excitation * (1-r^2) sin(th);  out = sum_f y;  new_states = (y[T-1], y[T-2])
//
// R8: single cooperative kernel, LDS-persistent chunk maps (no Aws):
// P1: 2 groups/block: build chunk maps (direct strided loads, R6-style),
//     wave-per-formant inclusive scan IN LDS; group products -> Gprod.
// P3: blocks 0..159: wave-scan over NG=47 group products -> Sg + new_states.
// P5: replay both groups from retained LDS maps + re-read inputs (L3-warm);
//     f-sum via padded LDS red; coalesced stores.
// Fallback: R6 3-kernel path if cooperative launch unsupported.

constexpr int B = 32;
constexpr int T = 48000;
constexpr int F = 5;
constexpr int L = 16;          // chunk length
constexpr int C = T / L;       // 3000 chunks per chain
constexpr int GS = 64;         // chunks per group (one wave per formant)
constexpr int NG = (C + GS - 1) / GS;  // 47 groups
constexpr int NCHAIN = B * F;  // 160
constexpr int THREADS = GS * F;        // 320 = 5 waves
constexpr int NBG = B * NG;            // 1504 (b,group) tiles
constexpr int GRID = 768;              // 3 blocks/CU exactly; 2 rounds
constexpr int MSTRIDE = 7;             // map stride in floats
constexpr int MROW = GS * MSTRIDE + 1; // 449: row stride ≡ 1 mod 32 (bank-spread)
constexpr int RROW = GS * (L + 1) + 1; // 1089: same trick for red

#define CBW2 (-9.4416635e-05f)   // -pi/(48000*ln2)
#define CCF  (1.3089969e-04f)    // 2*pi/48000

__device__ __forceinline__ float fast_exp2(float x) {
#if __has_builtin(__builtin_amdgcn_exp2f)
  return __builtin_amdgcn_exp2f(x);
#else
  return exp2f(x);
#endif
}

// Affine chunk map for chunk c of chain (b,f): columns u,v + offset w.
__device__ __forceinline__ void chunk_map(
    const float* __restrict__ exc, const float* __restrict__ cf,
    const float* __restrict__ bw, int b, int c, int f,
    float& u1, float& u2, float& v1, float& v2, float& w1, float& w2) {
  int t0 = c * L;
  const float* cfp = cf + ((size_t)b * T + t0) * F + f;
  const float* bwp = bw + ((size_t)b * T + t0) * F + f;
  const float* ep  = exc + (size_t)b * T + t0;
  #pragma unroll
  for (int i = 0; i < L; ++i) {
    float bwf = bwp[i * F];
    float cff = cfp[i * F];
    float e   = ep[i];
    float r  = fast_exp2(CBW2 * bwf);
    float th = CCF * cff;
    float sn = __sinf(th);
    float cs = __cosf(th);
    float p = 2.f * r * cs;     // -a1
    float q = -r * r;           // -a2
    float g = fmaf(q, sn, sn);  // (1-r^2) sin(th)
    float x = e * g;
    float nu = fmaf(p, u1, q * u2);
    float nv = fmaf(p, v1, q * v2);
    float nw = fmaf(p, w1, fmaf(q, w2, x));
    u2 = u1; u1 = nu;
    v2 = v1; v1 = nv;
    w2 = w1; w1 = nw;
  }
}

// Inclusive Hillis-Steele scan of affine maps across a wave (newest-on-left).
__device__ __forceinline__ void wave_scan_maps(int lane, float& u1, float& u2,
                                               float& v1, float& v2,
                                               float& w1, float& w2) {
  #pragma unroll
  for (int d = 1; d < 64; d <<= 1) {
    float pu1 = __shfl_up(u1, d);
    float pv1 = __shfl_up(v1, d);
    float pu2 = __shfl_up(u2, d);
    float pv2 = __shfl_up(v2, d);
    float pw1 = __shfl_up(w1, d);
    float pw2 = __shfl_up(w2, d);
    bool has = (lane >= d);
    pu1 = has ? pu1 : 1.f;  pv1 = has ? pv1 : 0.f;
    pu2 = has ? pu2 : 0.f;  pv2 = has ? pv2 : 1.f;
    pw1 = has ? pw1 : 0.f;  pw2 = has ? pw2 : 0.f;
    float nu1 = fmaf(u1, pu1, v1 * pu2);
    float nv1 = fmaf(u1, pv1, v1 * pv2);
    float nu2 = fmaf(u2, pu1, v2 * pu2);
    float nv2 = fmaf(u2, pv1, v2 * pv2);
    float nw1 = fmaf(u1, pw1, fmaf(v1, pw2, w1));
    float nw2 = fmaf(u2, pw1, fmaf(v2, pw2, w2));
    u1 = nu1; v1 = nv1; u2 = nu2; v2 = nv2; w1 = nw1; w2 = nw2;
  }
}

struct SharedF {
  float smaps[2][F][MROW];   // scanned maps, persist P1 -> P5 (17.96 KB)
  float red[F][RROW];        // replay y buffer (21.78 KB)
};

__global__ __launch_bounds__(THREADS, 4) void fused_kernel(
    const float* __restrict__ exc, const float* __restrict__ cf,
    const float* __restrict__ bw, const float* __restrict__ states0,
    float* __restrict__ out, float* __restrict__ out_states,
    float* __restrict__ Gprod, float* __restrict__ Sg) {
  __shared__ SharedF sh;
  cg::grid_group grid = cg::this_grid();

  int tid = threadIdx.x;
  int c_local = tid / F;
  int f = tid % F;
  int w = tid >> 6;       // wave id == formant id for scan phase
  int lane = tid & 63;

  // ---- P1: build + scan maps for (up to) 2 groups, keep in LDS ----
  for (int rr = 0; rr < 2; ++rr) {
    int bg = blockIdx.x + rr * GRID;
    if (bg < NBG) {
      int b = bg / NG, g = bg % NG;
      int c = g * GS + c_local;
      float u1 = 1.f, u2 = 0.f, v1 = 0.f, v2 = 1.f, w1 = 0.f, w2 = 0.f;
      if (c < C) chunk_map(exc, cf, bw, b, c, f, u1, u2, v1, v2, w1, w2);
      float* m = &sh.smaps[rr][f][c_local * MSTRIDE];
      m[0] = u1; m[1] = u2; m[2] = v1; m[3] = v2; m[4] = w1; m[5] = w2;
    }
    __syncthreads();
    if (bg < NBG) {
      int b = bg / NG, g = bg % NG;
      float* s = &sh.smaps[rr][w][lane * MSTRIDE];
      float a1 = s[0], a2 = s[1], a3 = s[2], a4 = s[3], a5 = s[4], a6 = s[5];
      wave_scan_maps(lane, a1, a2, a3, a4, a5, a6);
      // write back scanned (each lane owns its slot; wave-synchronous safe)
      s[0] = a1; s[1] = a2; s[2] = a3; s[3] = a4; s[4] = a5; s[5] = a6;
      if (lane == 63) {
        int chain = b * F + w;
        float4* gp = (float4*)(Gprod + (size_t)(chain * NG + g) * 8);
        gp[0] = make_float4(a1, a2, a3, a4);
        gp[1] = make_float4(a5, a6, 0.f, 0.f);
      }
    }
    __syncthreads();
  }

  grid.sync();

  // ---- P3: per-chain scan over group products (blocks 0..159, wave 0) ----
  if (blockIdx.x < NCHAIN && tid < 64) {
    int chain = blockIdx.x;
    float u1 = 1.f, u2 = 0.f, v1 = 0.f, v2 = 1.f, w1 = 0.f, w2 = 0.f;
    if (lane < NG) {
      const float4* gp = (const float4*)(Gprod + (size_t)(chain * NG + lane) * 8);
      float4 A0 = gp[0];
      float4 A1 = gp[1];
      u1 = A0.x; u2 = A0.y; v1 = A0.z; v2 = A0.w; w1 = A1.x; w2 = A1.y;
    }
    wave_scan_maps(lane, u1, u2, v1, v2, w1, w2);

    float s01 = states0[chain * 2 + 0];
    float s02 = states0[chain * 2 + 1];

    float eu1 = __shfl_up(u1, 1), ev1 = __shfl_up(v1, 1);
    float eu2 = __shfl_up(u2, 1), ev2 = __shfl_up(v2, 1);
    float ew1 = __shfl_up(w1, 1), ew2 = __shfl_up(w2, 1);
    if (lane == 0) { eu1 = 1.f; ev1 = 0.f; eu2 = 0.f; ev2 = 1.f; ew1 = 0.f; ew2 = 0.f; }
    if (lane < NG) {
      float sy1 = fmaf(eu1, s01, fmaf(ev1, s02, ew1));
      float sy2 = fmaf(eu2, s01, fmaf(ev2, s02, ew2));
      *(float2*)(Sg + (size_t)(chain * NG + lane) * 2) = make_float2(sy1, sy2);
    }
    float ay1 = fmaf(u1, s01, fmaf(v1, s02, w1));
    float ay2 = fmaf(u2, s01, fmaf(v2, s02, w2));
    float fy1 = __shfl(ay1, 63);
    float fy2 = __shfl(ay2, 63);
    if (lane == 0) {
      out_states[chain * 2 + 0] = fy1;
      out_states[chain * 2 + 1] = fy2;
    }
  }

  grid.sync();

  // ---- P5: replay from retained LDS maps; f-sum; store ----
  for (int rr = 0; rr < 2; ++rr) {
    int bg = blockIdx.x + rr * GRID;
    if (bg < NBG) {
      int b = bg / NG, g = bg % NG;
      int c = g * GS + c_local;
      if (c < C) {
        int chain = b * F + f;
        float2 sg = *(const float2*)(Sg + (size_t)(chain * NG + g) * 2);
        float y1, y2;
        if (c_local == 0) {
          y1 = sg.x;
          y2 = sg.y;
        } else {
          const float* m = &sh.smaps[rr][f][(c_local - 1) * MSTRIDE];
          y1 = fmaf(m[0], sg.x, fmaf(m[2], sg.y, m[4]));
          y2 = fmaf(m[1], sg.x, fmaf(m[3], sg.y, m[5]));
        }

        int t0 = c * L;
        const float* cfp = cf + ((size_t)b * T + t0) * F + f;
        const float* bwp = bw + ((size_t)b * T + t0) * F + f;
        const float* ep  = exc + (size_t)b * T + t0;

        #pragma unroll
        for (int i = 0; i < L; ++i) {
          float bwf = bwp[i * F];
          float cff = cfp[i * F];
          float e   = ep[i];
          float r  = fast_exp2(CBW2 * bwf);
          float th = CCF * cff;
          float sn = __sinf(th);
          float cs = __cosf(th);
          float p = 2.f * r * cs;
          float q = -r * r;
          float gn = fmaf(q, sn, sn);
          float x = e * gn;
          float y = fmaf(p, y1, fmaf(q, y2, x));
          sh.red[f][c_local * (L + 1) + i] = y;
          y2 = y1;
          y1 = y;
        }
      }
    }
    __syncthreads();
    if (bg < NBG) {
      int b = bg / NG, g = bg % NG;
      int c0 = g * GS;
      int nc = (C - c0 < GS) ? (C - c0) : GS;
      int nt = nc * L;
      size_t tbase = (size_t)b * T + (size_t)c0 * L;
      for (int t = tid; t < nt; t += THREADS) {
        int a = (t >> 4) * (L + 1) + (t & (L - 1));
        float s = sh.red[0][a] + sh.red[1][a] + sh.red[2][a] + sh.red[3][a] +
                  sh.red[4][a];
        out[tbase + t] = s;
      }
    }
    __syncthreads();
  }
}

// ---------------- fallback: R6 3-kernel path ----------------

constexpr int MROW6 = GS * MSTRIDE;

__global__ __launch_bounds__(THREADS) void k1_kernel(
    const float* __restrict__ exc, const float* __restrict__ cf,
    const float* __restrict__ bw, float* __restrict__ Aws,
    float* __restrict__ Gprod) {
  __shared__ float smaps[F][MROW6];
  int bg = blockIdx.x;
  int b = bg / NG, g = bg % NG;
  int tid = threadIdx.x;
  int c_local = tid / F, f = tid % F;
  int c = g * GS + c_local;

  float u1 = 1.f, u2 = 0.f, v1 = 0.f, v2 = 1.f, w1 = 0.f, w2 = 0.f;
  if (c < C) chunk_map(exc, cf, bw, b, c, f, u1, u2, v1, v2, w1, w2);
  float* m = &smaps[f][c_local * MSTRIDE];
  m[0] = u1; m[1] = u2; m[2] = v1; m[3] = v2; m[4] = w1; m[5] = w2;
  __syncthreads();

  int w = tid >> 6, lane = tid & 63;
  const float* s = &smaps[w][lane * MSTRIDE];
  float a1 = s[0], a2 = s[1], a3 = s[2], a4 = s[3], a5 = s[4], a6 = s[5];
  wave_scan_maps(lane, a1, a2, a3, a4, a5, a6);

  int c2 = g * GS + lane;
  int chain = b * F + w;
  if (c2 < C) {
    float4* o = (float4*)(Aws + ((size_t)chain * C + c2) * 8);
    o[0] = make_float4(a1, a2, a3, a4);
    o[1] = make_float4(a5, a6, 0.f, 0.f);
  }
  if (lane == 63) {
    float4* gp = (float4*)(Gprod + (size_t)(chain * NG + g) * 8);
    gp[0] = make_float4(a1, a2, a3, a4);
    gp[1] = make_float4(a5, a6, 0.f, 0.f);
  }
}

__global__ __launch_bounds__(64) void k2_kernel(
    const float* __restrict__ Gprod, const float* __restrict__ states0,
    float* __restrict__ Sg, float* __restrict__ out_states) {
  int chain = blockIdx.x;
  int lane = threadIdx.x;
  float u1 = 1.f, u2 = 0.f, v1 = 0.f, v2 = 1.f, w1 = 0.f, w2 = 0.f;
  if (lane < NG) {
    const float4* gp = (const float4*)(Gprod + (size_t)(chain * NG + lane) * 8);
    float4 A0 = gp[0];
    float4 A1 = gp[1];
    u1 = A0.x; u2 = A0.y; v1 = A0.z; v2 = A0.w; w1 = A1.x; w2 = A1.y;
  }
  wave_scan_maps(lane, u1, u2, v1, v2, w1, w2);
  float s01 = states0[chain * 2 + 0];
  float s02 = states0[chain * 2 + 1];
  float eu1 = __shfl_up(u1, 1), ev1 = __shfl_up(v1, 1);
  float eu2 = __shfl_up(u2, 1), ev2 = __shfl_up(v2, 1);
  float ew1 = __shfl_up(w1, 1), ew2 = __shfl_up(w2, 1);
  if (lane == 0) { eu1 = 1.f; ev1 = 0.f; eu2 = 0.f; ev2 = 1.f; ew1 = 0.f; ew2 = 0.f; }
  if (lane < NG) {
    float sy1 = fmaf(eu1, s01, fmaf(ev1, s02, ew1));
    float sy2 = fmaf(eu2, s01, fmaf(ev2, s02, ew2));
    *(float2*)(Sg + (size_t)(chain * NG + lane) * 2) = make_float2(sy1, sy2);
  }
  float ay1 = fmaf(u1, s01, fmaf(v1, s02, w1));
  float ay2 = fmaf(u2, s01, fmaf(v2, s02, w2));
  float fy1 = __shfl(ay1, 63);
  float fy2 = __shfl(ay2, 63);
  if (lane == 0) {
    out_states[chain * 2 + 0] = fy1;
    out_states[chain * 2 + 1] = fy2;
  }
}

constexpr int P3_ROW = GS * (L + 1);

__global__ __launch_bounds__(THREADS) void k3_kernel(
    const float* __restrict__ exc, const float* __restrict__ cf,
    const float* __restrict__ bw, const float* __restrict__ Aws,
    const float* __restrict__ Sg, float* __restrict__ out) {
  __shared__ float red[F][P3_ROW];
  int bg = blockIdx.x;
  int b = bg / NG, g = bg % NG;
  int c0 = g * GS;
  int nc = (C - c0 < GS) ? (C - c0) : GS;
  int tid = threadIdx.x;
  int c_local = tid / F, f = tid % F;

  if (c_local < nc) {
    int c = c0 + c_local;
    int chain = b * F + f;
    float2 sg = *(const float2*)(Sg + (size_t)(chain * NG + g) * 2);
    float y1, y2;
    if (c_local == 0) {
      y1 = sg.x; y2 = sg.y;
    } else {
      const float4* m = (const float4*)(Aws + ((size_t)chain * C + (c - 1)) * 8);
      float4 M0 = m[0];
      float4 M1 = m[1];
      y1 = fmaf(M0.x, sg.x, fmaf(M0.z, sg.y, M1.x));
      y2 = fmaf(M0.y, sg.x, fmaf(M0.w, sg.y, M1.y));
    }
    int t0 = c * L;
    const float* cfp = cf + ((size_t)b * T + t0) * F + f;
    const float* bwp = bw + ((size_t)b * T + t0) * F + f;
    const float* ep  = exc + (size_t)b * T + t0;
    #pragma unroll
    for (int i = 0; i < L; ++i) {
      float bwf = bwp[i * F];
      float cff = cfp[i * F];
      float e   = ep[i];
      float r  = fast_exp2(CBW2 * bwf);
      float th = CCF * cff;
      float sn = __sinf(th);
      float cs = __cosf(th);
      float p = 2.f * r * cs;
      float q = -r * r;
      float gn = fmaf(q, sn, sn);
      float x = e * gn;
      float y = fmaf(p, y1, fmaf(q, y2, x));
      red[f][c_local * (L + 1) + i] = y;
      y2 = y1;
      y1 = y;
    }
  }
  __syncthreads();
  int nt = nc * L;
  size_t tbase = (size_t)b * T + (size_t)c0 * L;
  for (int t = tid; t < nt; t += THREADS) {
    int ci = t >> 4, ii = t & (L - 1);
    int a = ci * (L + 1) + ii;
    float s = red[0][a] + red[1][a] + red[2][a] + red[3][a] + red[4][a];
    out[tbase + t] = s;
  }
}

extern "C" void kernel_launch(void* const* d_in, const int* in_sizes, int n_in,
                              void* d_out, int out_size, void* d_ws, size_t ws_size,
                              hipStream_t stream) {
  const float* exc = (const float*)d_in[0];   // (B,T,1)
  const float* cf  = (const float*)d_in[1];   // (B,T,F)
  const float* bw  = (const float*)d_in[2];   // (B,T,F)
  const float* st  = (const float*)d_in[3];   // (B,F,2)
  float* out        = (float*)d_out;          // (B,T,1) then (B,F,2)
  float* out_states = out + (size_t)B * T;

  float* Aws   = (float*)d_ws;                       // fallback only (15.36 MB)
  float* Gprod = Aws + (size_t)NCHAIN * C * 8;       // NCHAIN*NG*8 floats
  float* Sg    = Gprod + (size_t)NCHAIN * NG * 8;    // NCHAIN*NG*2 floats

  void* args[] = {(void*)&exc, (void*)&cf, (void*)&bw, (void*)&st,
                  (void*)&out, (void*)&out_states, (void*)&Gprod, (void*)&Sg};
  hipError_t err = hipLaunchCooperativeKernel((const void*)fused_kernel,
                                              dim3(GRID), dim3(THREADS),
                                              args, 0, stream);
  if (err != hipSuccess) {
    (void)hipGetLastError();  // clear; deterministic fallback path
    k1_kernel<<<NBG, THREADS, 0, stream>>>(exc, cf, bw, Aws, Gprod);
    k2_kernel<<<NCHAIN, 64, 0, stream>>>(Gprod, st, Sg, out_states);
    k3_kernel<<<NBG, THREADS, 0, stream>>>(exc, cf, bw, Aws, Sg, out);
  }
}

// Round 9
// 43.050 us; speedup vs baseline: 4.8640x; 4.8640x over previous
//
#include <hip/hip_runtime.h>

// StatefulFormantFilter: B=32, T=48000, F=5
// y[t] = x[t] + 2 r cos(th) y[t-1] - r^2 y[t-2],  r=exp(-pi bw/SR), th=2 pi cf/SR
// x = excitation * (1-r^2) sin(th);  out = sum_f y;  new_states = (y[T-1], y[T-2])
//
// R9 = R6 dataflow, 2 kernels:
// K1: block=(b, 64-chunk group): build chunk maps (software-pipelined loads:
//     float4 exc + 4-step cf/bw register tiles with lookahead), LDS exchange,
//     wave-per-formant inclusive scan -> Aws (cache-resident) + Gprod.
// K3: per block: 5 waves re-derive chain prefix by scanning the 47 group
//     products (L2-hot) -> entering state; g==0 blocks write new_states;
//     replay 16 steps (same pipelined loads); f-sum via LDS; coalesced store.
// NOTE (R8 lesson): cooperative grid.sync costs ~75us/sync on MI355X —
// kernel boundary is the cheap grid barrier.

constexpr int B = 32;
constexpr int T = 48000;
constexpr int F = 5;
constexpr int L = 16;          // chunk length
constexpr int C = T / L;       // 3000 chunks per chain
constexpr int GS = 64;         // chunks per group (one wave per formant)
constexpr int NG = (C + GS - 1) / GS;  // 47 groups
constexpr int NCHAIN = B * F;  // 160
constexpr int THREADS = GS * F;        // 320 = 5 waves
constexpr int NBG = B * NG;            // 1504 (b,group) tiles
constexpr int MSTRIDE = 7;             // map stride in floats
constexpr int MROW = GS * MSTRIDE + 1; // 449: row ≡ 1 mod 32 -> f spreads banks
constexpr int RROW = GS * (L + 1) + 1; // 1089: same bank trick for red

#define CBW2 (-9.4416635e-05f)   // -pi/(48000*ln2)
#define CCF  (1.3089969e-04f)    // 2*pi/48000

__device__ __forceinline__ float fast_exp2(float x) {
#if __has_builtin(__builtin_amdgcn_exp2f)
  return __builtin_amdgcn_exp2f(x);
#else
  return exp2f(x);
#endif
}

__device__ __forceinline__ void coef(float cff, float bwf, float e,
                                     float& p, float& q, float& x) {
  float r  = fast_exp2(CBW2 * bwf);
  float th = CCF * cff;
  float sn = __sinf(th);
  float cs = __cosf(th);
  p = 2.f * r * cs;            // -a1
  q = -r * r;                  // -a2
  x = e * fmaf(q, sn, sn);     // e * (1-r^2) sin(th)
}

// Inclusive Hillis-Steele scan of affine maps across a wave (newest-on-left).
__device__ __forceinline__ void wave_scan_maps(int lane, float& u1, float& u2,
                                               float& v1, float& v2,
                                               float& w1, float& w2) {
  #pragma unroll
  for (int d = 1; d < 64; d <<= 1) {
    float pu1 = __shfl_up(u1, d);
    float pv1 = __shfl_up(v1, d);
    float pu2 = __shfl_up(u2, d);
    float pv2 = __shfl_up(v2, d);
    float pw1 = __shfl_up(w1, d);
    float pw2 = __shfl_up(w2, d);
    bool has = (lane >= d);
    pu1 = has ? pu1 : 1.f;  pv1 = has ? pv1 : 0.f;
    pu2 = has ? pu2 : 0.f;  pv2 = has ? pv2 : 1.f;
    pw1 = has ? pw1 : 0.f;  pw2 = has ? pw2 : 0.f;
    float nu1 = fmaf(u1, pu1, v1 * pu2);
    float nv1 = fmaf(u1, pv1, v1 * pv2);
    float nu2 = fmaf(u2, pu1, v2 * pu2);
    float nv2 = fmaf(u2, pv1, v2 * pv2);
    float nw1 = fmaf(u1, pw1, fmaf(v1, pw2, w1));
    float nw2 = fmaf(u2, pw1, fmaf(v2, pw2, w2));
    u1 = nu1; v1 = nv1; u2 = nu2; v2 = nv2; w1 = nw1; w2 = nw2;
  }
}

__global__ __launch_bounds__(THREADS) void k1_kernel(
    const float* __restrict__ exc, const float* __restrict__ cf,
    const float* __restrict__ bw, float* __restrict__ Aws,
    float* __restrict__ Gprod) {
  __shared__ float smaps[F][MROW];

  int bg = blockIdx.x;
  int b = bg / NG, g = bg % NG;
  int tid = threadIdx.x;
  int c_local = tid / F, f = tid % F;
  int c = g * GS + c_local;

  float u1 = 1.f, u2 = 0.f, v1 = 0.f, v2 = 1.f, w1 = 0.f, w2 = 0.f;
  if (c < C) {
    const float* cfp = cf + ((size_t)b * T + c * L) * F + f;
    const float* bwp = bw + ((size_t)b * T + c * L) * F + f;
    const float4* ep4 = (const float4*)(exc + (size_t)b * T + c * L);

    float4 e = ep4[0];
    float cfa[4], bwa[4];
    #pragma unroll
    for (int j = 0; j < 4; ++j) { cfa[j] = cfp[j * F]; bwa[j] = bwp[j * F]; }

    #pragma unroll
    for (int tile = 0; tile < 4; ++tile) {
      float4 en;
      float cfn[4], bwn[4];
      if (tile < 3) {   // issue next tile's loads before computing this one
        en = ep4[tile + 1];
        #pragma unroll
        for (int j = 0; j < 4; ++j) {
          cfn[j] = cfp[(tile * 4 + 4 + j) * F];
          bwn[j] = bwp[(tile * 4 + 4 + j) * F];
        }
      }
      #pragma unroll
      for (int j = 0; j < 4; ++j) {
        float p, q, x;
        coef(cfa[j], bwa[j], (&e.x)[j], p, q, x);
        float nu = fmaf(p, u1, q * u2);
        float nv = fmaf(p, v1, q * v2);
        float nw = fmaf(p, w1, fmaf(q, w2, x));
        u2 = u1; u1 = nu;
        v2 = v1; v1 = nv;
        w2 = w1; w1 = nw;
      }
      if (tile < 3) {
        e = en;
        #pragma unroll
        for (int j = 0; j < 4; ++j) { cfa[j] = cfn[j]; bwa[j] = bwn[j]; }
      }
    }
  }

  {
    float* m = &smaps[f][c_local * MSTRIDE];
    m[0] = u1; m[1] = u2; m[2] = v1; m[3] = v2; m[4] = w1; m[5] = w2;
  }
  __syncthreads();

  int w = tid >> 6, lane = tid & 63;
  const float* s = &smaps[w][lane * MSTRIDE];
  float a1 = s[0], a2 = s[1], a3 = s[2], a4 = s[3], a5 = s[4], a6 = s[5];
  wave_scan_maps(lane, a1, a2, a3, a4, a5, a6);

  int c2 = g * GS + lane;
  int chain = b * F + w;
  if (c2 < C) {
    float4* o = (float4*)(Aws + ((size_t)chain * C + c2) * 8);
    o[0] = make_float4(a1, a2, a3, a4);
    o[1] = make_float4(a5, a6, 0.f, 0.f);
  }
  if (lane == 63) {
    float4* gp = (float4*)(Gprod + (size_t)(chain * NG + g) * 8);
    gp[0] = make_float4(a1, a2, a3, a4);
    gp[1] = make_float4(a5, a6, 0.f, 0.f);
  }
}

__global__ __launch_bounds__(THREADS) void k3_kernel(
    const float* __restrict__ exc, const float* __restrict__ cf,
    const float* __restrict__ bw, const float* __restrict__ Aws,
    const float* __restrict__ Gprod, const float* __restrict__ states0,
    float* __restrict__ out, float* __restrict__ out_states) {
  __shared__ float red[F][RROW];
  __shared__ float2 sgb[F];

  int bg = blockIdx.x;
  int b = bg / NG, g = bg % NG;
  int c0 = g * GS;
  int nc = (C - c0 < GS) ? (C - c0) : GS;
  int tid = threadIdx.x;
  int c_local = tid / F, f = tid % F;
  int w = tid >> 6, lane = tid & 63;

  // --- per-block chain prefix: wave w scans formant w's 47 group products ---
  {
    int chain = b * F + w;
    float u1 = 1.f, u2 = 0.f, v1 = 0.f, v2 = 1.f, w1 = 0.f, w2 = 0.f;
    if (lane < NG) {
      const float4* gp = (const float4*)(Gprod + (size_t)(chain * NG + lane) * 8);
      float4 A0 = gp[0];
      float4 A1 = gp[1];
      u1 = A0.x; u2 = A0.y; v1 = A0.z; v2 = A0.w; w1 = A1.x; w2 = A1.y;
    }
    wave_scan_maps(lane, u1, u2, v1, v2, w1, w2);

    float s01 = states0[chain * 2 + 0];
    float s02 = states0[chain * 2 + 1];
    if (g == 0) {
      if (lane == 0) sgb[w] = make_float2(s01, s02);
      if (lane == NG - 1) {   // full-chain product -> new_states (once per chain)
        out_states[chain * 2 + 0] = fmaf(u1, s01, fmaf(v1, s02, w1));
        out_states[chain * 2 + 1] = fmaf(u2, s01, fmaf(v2, s02, w2));
      }
    } else if (lane == g - 1) {  // exclusive prefix before group g
      float sy1 = fmaf(u1, s01, fmaf(v1, s02, w1));
      float sy2 = fmaf(u2, s01, fmaf(v2, s02, w2));
      sgb[w] = make_float2(sy1, sy2);
    }
  }
  __syncthreads();

  // --- replay ---
  if (c_local < nc) {
    int c = c0 + c_local;
    int chain = b * F + f;

    float2 sg = sgb[f];
    float y1, y2;
    if (c_local == 0) {
      y1 = sg.x; y2 = sg.y;
    } else {
      const float4* m = (const float4*)(Aws + ((size_t)chain * C + (c - 1)) * 8);
      float4 M0 = m[0];
      float4 M1 = m[1];
      y1 = fmaf(M0.x, sg.x, fmaf(M0.z, sg.y, M1.x));
      y2 = fmaf(M0.y, sg.x, fmaf(M0.w, sg.y, M1.y));
    }

    const float* cfp = cf + ((size_t)b * T + c * L) * F + f;
    const float* bwp = bw + ((size_t)b * T + c * L) * F + f;
    const float4* ep4 = (const float4*)(exc + (size_t)b * T + c * L);

    float4 e = ep4[0];
    float cfa[4], bwa[4];
    #pragma unroll
    for (int j = 0; j < 4; ++j) { cfa[j] = cfp[j * F]; bwa[j] = bwp[j * F]; }

    float* rrow = &red[f][c_local * (L + 1)];
    #pragma unroll
    for (int tile = 0; tile < 4; ++tile) {
      float4 en;
      float cfn[4], bwn[4];
      if (tile < 3) {
        en = ep4[tile + 1];
        #pragma unroll
        for (int j = 0; j < 4; ++j) {
          cfn[j] = cfp[(tile * 4 + 4 + j) * F];
          bwn[j] = bwp[(tile * 4 + 4 + j) * F];
        }
      }
      #pragma unroll
      for (int j = 0; j < 4; ++j) {
        float p, q, x;
        coef(cfa[j], bwa[j], (&e.x)[j], p, q, x);
        float y = fmaf(p, y1, fmaf(q, y2, x));
        rrow[tile * 4 + j] = y;
        y2 = y1;
        y1 = y;
      }
      if (tile < 3) {
        e = en;
        #pragma unroll
        for (int j = 0; j < 4; ++j) { cfa[j] = cfn[j]; bwa[j] = bwn[j]; }
      }
    }
  }
  __syncthreads();

  // --- f-sum + coalesced store ---
  int nt = nc * L;
  size_t tbase = (size_t)b * T + (size_t)c0 * L;
  for (int t = tid; t < nt; t += THREADS) {
    int a = (t >> 4) * (L + 1) + (t & (L - 1));
    float s = red[0][a] + red[1][a] + red[2][a] + red[3][a] + red[4][a];
    out[tbase + t] = s;
  }
}

extern "C" void kernel_launch(void* const* d_in, const int* in_sizes, int n_in,
                              void* d_out, int out_size, void* d_ws, size_t ws_size,
                              hipStream_t stream) {
  const float* exc = (const float*)d_in[0];   // (B,T,1)
  const float* cf  = (const float*)d_in[1];   // (B,T,F)
  const float* bw  = (const float*)d_in[2];   // (B,T,F)
  const float* st  = (const float*)d_in[3];   // (B,F,2)
  float* out        = (float*)d_out;          // (B,T,1) then (B,F,2)
  float* out_states = out + (size_t)B * T;

  float* Aws   = (float*)d_ws;                       // NCHAIN*C*8 floats = 15.36 MB
  float* Gprod = Aws + (size_t)NCHAIN * C * 8;       // NCHAIN*NG*8 floats = 240 KB

  k1_kernel<<<NBG, THREADS, 0, stream>>>(exc, cf, bw, Aws, Gprod);
  k3_kernel<<<NBG, THREADS, 0, stream>>>(exc, cf, bw, Aws, Gprod, st, out,
                                         out_states);
}